// Round 3
// baseline (511.033 us; speedup 1.0000x reference)
//
#include <hip/hip_runtime.h>

constexpr int D_IN  = 64;
constexpr int D_H1  = 32;
constexpr int D_H2  = 64;
constexpr int D_OUT = 128;
constexpr int NSEG  = 8192;

constexpr int BLOCK = 256;       // 4 waves
constexpr int RT    = 64;        // rows per tile
constexpr int TPB   = 8;         // tiles per block -> 1954 blocks

typedef __bf16 bfx8 __attribute__((ext_vector_type(8)));
typedef __bf16 bfx4 __attribute__((ext_vector_type(4)));
typedef float  fx4  __attribute__((ext_vector_type(4)));

// MFMA 16x16x32 bf16 layouts (m89-verified):
//   A: m = lane&15, k = (lane>>4)*8 + j
//   B: n = lane&15, k = (lane>>4)*8 + i   (same lane->element map as A!)
//   D: row(m) = (lane>>4)*4 + reg, col(n) = lane&15
// L1/L2 use SWAPPED operands (W as A, h as B): D = (h*W)^T, so each lane
// holds 4 CONTIGUOUS output features of one data row -> bfx4 epilogue writes.

// Raw barrier with LDS-only ordering: avoids __syncthreads' vmcnt(0) drain
// so prefetch global loads stay in flight across the barrier.
#define BAR_LGKM() do {                                        \
    asm volatile("s_waitcnt lgkmcnt(0)" ::: "memory");         \
    __builtin_amdgcn_s_barrier();                              \
    __builtin_amdgcn_sched_barrier(0);                         \
} while (0)

__global__ __launch_bounds__(BLOCK, 4) void mlp_seg_mfma(
    const float* __restrict__ f, const int* __restrict__ seg,
    const float* __restrict__ W1, const float* __restrict__ b1,
    const float* __restrict__ W2, const float* __restrict__ b2,
    const float* __restrict__ W3, const float* __restrict__ b3,
    float* __restrict__ sums, float* __restrict__ counts,
    int N, int ntiles)
{
    __shared__ __align__(16) __bf16 sf [RT * 64];    // 8 KB single buffer (barrier-protected in-place refill)
    __shared__ __align__(16) __bf16 sh1[RT * 32];    // 4 KB
    __shared__ __align__(16) __bf16 sh2[RT * 64];    // 8 KB
    __shared__ __align__(16) __bf16 syT[D_OUT * 64]; // 16 KB transposed [col][row], XOR-swizzled
    __shared__ int sseg[2][RT];                      // seg ids double-buffered (scan reads after BAR2)

    const int tid  = threadIdx.x;
    const int wv   = tid >> 6;
    const int lane = tid & 63;
    const int lr   = lane & 15;
    const int quad = lane >> 4;
    const int m0   = wv * 16;          // this wave's 16-row slice for L1/L2
    const int ar   = m0 + lr;          // data row for this lane (L1/L2)

    // ---- weight fragments + biases -> registers (one-time, L2-cached) ----
    bfx8 fw1[2][2];                    // [ntile][kstep]  W1[64][32]
    #pragma unroll
    for (int j = 0; j < 2; ++j)
        #pragma unroll
        for (int ks = 0; ks < 2; ++ks)
            #pragma unroll
            for (int i = 0; i < 8; ++i)
                fw1[j][ks][i] = (__bf16)W1[(ks*32 + quad*8 + i)*D_H1 + j*16 + lr];

    bfx8 fw2[4];                       // W2[32][64], K=32 single step
    #pragma unroll
    for (int j = 0; j < 4; ++j)
        #pragma unroll
        for (int i = 0; i < 8; ++i)
            fw2[j][i] = (__bf16)W2[(quad*8 + i)*D_H2 + j*16 + lr];

    bfx8 fw3[2][2];                    // W3[64][128], cols wv*32 + j*16 + lr (per-wave col slice)
    #pragma unroll
    for (int j = 0; j < 2; ++j)
        #pragma unroll
        for (int ks = 0; ks < 2; ++ks)
            #pragma unroll
            for (int i = 0; i < 8; ++i)
                fw3[j][ks][i] = (__bf16)W3[(ks*32 + quad*8 + i)*D_OUT + wv*32 + j*16 + lr];

    // biases per-lane for swapped-D layout: feature = j*16 + quad*4 + rg
    fx4 rb1v[2], rb2v[4];
    #pragma unroll
    for (int j = 0; j < 2; ++j)
        #pragma unroll
        for (int rg = 0; rg < 4; ++rg) rb1v[j][rg] = b1[j*16 + quad*4 + rg];
    #pragma unroll
    for (int j = 0; j < 4; ++j)
        #pragma unroll
        for (int rg = 0; rg < 4; ++rg) rb2v[j][rg] = b2[j*16 + quad*4 + rg];
    float rb3[2];
    #pragma unroll
    for (int j = 0; j < 2; ++j) rb3[j] = b3[wv*32 + j*16 + lr];

    // ---- persistent segment-run state (two 128-thread groups) ----
    const int colA = tid & 127;        // owned output column
    const int grp  = tid >> 7;         // group 0: rows 0..31, group 1: rows 32..63
    int   cur_seg = -1;
    float run_sum = 0.f;
    int   run_len = 0;

    const int t0 = blockIdx.x * TPB;
    const int t1 = min(t0 + TPB, ntiles);

    // ---- prologue: stage tile t0 ----
    {
        const int R0 = t0 * RT;
        const float4* f4 = (const float4*)f + (size_t)R0 * 16;
        #pragma unroll
        for (int i = 0; i < 4; ++i) {
            const int idx4 = tid + i * 256;
            float4 qq = make_float4(0.f, 0.f, 0.f, 0.f);
            if ((size_t)R0 * 64 + (size_t)idx4 * 4 < (size_t)N * 64) qq = f4[idx4];
            const int r = idx4 >> 4;
            const int c = (idx4 & 15) * 4;
            bfx4 v;
            v[0] = (__bf16)qq.x; v[1] = (__bf16)qq.y;
            v[2] = (__bf16)qq.z; v[3] = (__bf16)qq.w;
            *(bfx4*)&sf[r*64 + (((c >> 3) ^ (r & 7)) << 3) + (c & 7)] = v;
        }
        if (tid < RT) sseg[0][tid] = (R0 + tid < N) ? seg[R0 + tid] : -2;
    }
    __syncthreads();

    int p = 0;
    for (int t = t0; t < t1; ++t, p ^= 1) {
        const int R0 = t * RT;
        const bool havenext = (t + 1 < t1);

        // ---- issue next tile's global loads EARLY (latency hides under MLP) ----
        float4 q[4];
        int rseg = -2;
        if (havenext) {
            const float4* f4n = (const float4*)f + (size_t)(R0 + RT) * 16;
            #pragma unroll
            for (int i = 0; i < 4; ++i) {
                const int idx4 = tid + i * 256;
                q[i] = make_float4(0.f, 0.f, 0.f, 0.f);
                if ((size_t)(R0 + RT) * 64 + (size_t)idx4 * 4 < (size_t)N * 64)
                    q[i] = f4n[idx4];
            }
            if (tid < RT) rseg = (R0 + RT + tid < N) ? seg[R0 + RT + tid] : -2;
        }

        // ---- L1: h1^T = W1^T * f^T (swapped operands), rows m0..m0+15 ----
        fx4 acc1[2] = {{0,0,0,0},{0,0,0,0}};
        #pragma unroll
        for (int ks = 0; ks < 2; ++ks) {
            bfx8 a = *(const bfx8*)&sf[ar*64 + (((ks*4 + quad) ^ (ar & 7)) << 3)];
            #pragma unroll
            for (int j = 0; j < 2; ++j)
                acc1[j] = __builtin_amdgcn_mfma_f32_16x16x32_bf16(fw1[j][ks], a, acc1[j], 0, 0, 0);
        }
        #pragma unroll
        for (int j = 0; j < 2; ++j) {
            bfx4 w;
            #pragma unroll
            for (int rg = 0; rg < 4; ++rg)
                w[rg] = (__bf16)fmaxf(acc1[j][rg] + rb1v[j][rg], 0.f);
            // feature block b = (j*16+quad*4)>>3, intra-offset (quad&1)*4
            const int b = j*2 + (quad >> 1);
            *(bfx4*)&sh1[ar*32 + ((b ^ (ar & 3)) << 3) + (quad & 1)*4] = w;
        }
        // no barrier: sh1 rows [m0, m0+16) are written and read by this wave only

        // ---- L2: h2^T = W2^T * h1^T (swapped), K=32 single step ----
        fx4 acc2[4] = {{0,0,0,0},{0,0,0,0},{0,0,0,0},{0,0,0,0}};
        {
            bfx8 a = *(const bfx8*)&sh1[ar*32 + ((quad ^ (ar & 3)) << 3)];
            #pragma unroll
            for (int j = 0; j < 4; ++j)
                acc2[j] = __builtin_amdgcn_mfma_f32_16x16x32_bf16(fw2[j], a, acc2[j], 0, 0, 0);
        }
        #pragma unroll
        for (int j = 0; j < 4; ++j) {
            bfx4 w;
            #pragma unroll
            for (int rg = 0; rg < 4; ++rg)
                w[rg] = (__bf16)fmaxf(acc2[j][rg] + rb2v[j][rg], 0.f);
            const int b = j*2 + (quad >> 1);
            *(bfx4*)&sh2[ar*64 + ((b ^ (ar & 7)) << 3) + (quad & 1)*4] = w;
        }

        BAR_LGKM();   // all waves' sh2 writes visible; prefetch loads stay in flight

        // ---- L3: per-wave 32-col slice over ALL 64 rows (unswapped: D rows
        //      contiguous -> bfx4 into transposed syT) ----
        #pragma unroll
        for (int mt = 0; mt < 4; ++mt) {
            fx4 acc3[2] = {{0,0,0,0},{0,0,0,0}};
            const int arow = mt*16 + lr;
            #pragma unroll
            for (int ks = 0; ks < 2; ++ks) {
                bfx8 a = *(const bfx8*)&sh2[arow*64 + (((ks*4 + quad) ^ (arow & 7)) << 3)];
                #pragma unroll
                for (int j = 0; j < 2; ++j)
                    acc3[j] = __builtin_amdgcn_mfma_f32_16x16x32_bf16(a, fw3[j][ks], acc3[j], 0, 0, 0);
            }
            #pragma unroll
            for (int j = 0; j < 2; ++j) {
                bfx4 w;
                #pragma unroll
                for (int rg = 0; rg < 4; ++rg)
                    w[rg] = (__bf16)(acc3[j][rg] + rb3[j]);
                const int col  = wv*32 + j*16 + lr;
                const int row0 = mt*16 + quad*4;   // 4 contiguous rows
                *(bfx4*)&syT[col*64 + (((row0 >> 3) ^ (col & 7)) << 3) + (quad & 1)*4] = w;
            }
        }

        // ---- write prefetched tile in place (sf reads all happened pre-BAR1) ----
        if (havenext) {
            #pragma unroll
            for (int i = 0; i < 4; ++i) {
                const int idx4 = tid + i * 256;
                const int r = idx4 >> 4;
                const int c = (idx4 & 15) * 4;
                bfx4 v;
                v[0] = (__bf16)q[i].x; v[1] = (__bf16)q[i].y;
                v[2] = (__bf16)q[i].z; v[3] = (__bf16)q[i].w;
                *(bfx4*)&sf[r*64 + (((c >> 3) ^ (r & 7)) << 3) + (c & 7)] = v;
            }
            if (tid < RT) sseg[p ^ 1][tid] = rseg;
        }

        BAR_LGKM();   // syT + next-sf writes visible to all waves

        // ---- segment-run accumulation: 4 chunks of 8 rows, vectorized ----
        // seg_ids sorted => s[first]==s[last] implies whole chunk same segment.
        // Next iteration's BAR1 orders these reads against buffer overwrite.
        #pragma unroll
        for (int ch = 0; ch < 4; ++ch) {
            const int r8 = grp*32 + ch*8;
            const bfx8 v8 = *(const bfx8*)&syT[colA*64 + (((grp*4 + ch) ^ (colA & 7)) << 3)];
            const int sA = sseg[p][r8];
            const int sB = sseg[p][r8 + 7];
            if (sA == sB) {                            // fast path (~93% of chunks)
                float sum = 0.f;
                #pragma unroll
                for (int k = 0; k < 8; ++k) sum += (float)v8[k];
                if (sA != cur_seg) {                   // uniform within group
                    if (cur_seg >= 0) {
                        atomicAdd(&sums[(size_t)cur_seg * D_OUT + colA], run_sum);
                        if (colA == 0) atomicAdd(&counts[cur_seg], (float)run_len);
                    }
                    cur_seg = sA; run_sum = sum; run_len = 8;
                } else {
                    run_sum += sum; run_len += 8;
                }
            } else {                                   // boundary chunk: per-row, from regs
                #pragma unroll
                for (int k = 0; k < 8; ++k) {
                    const int s = sseg[p][r8 + k];
                    if (s != cur_seg) {
                        if (cur_seg >= 0) {
                            atomicAdd(&sums[(size_t)cur_seg * D_OUT + colA], run_sum);
                            if (colA == 0) atomicAdd(&counts[cur_seg], (float)run_len);
                        }
                        cur_seg = s; run_sum = 0.f; run_len = 0;
                    }
                    run_sum += (float)v8[k]; run_len++;
                }
            }
        }
    }

    if (cur_seg >= 0) {
        atomicAdd(&sums[(size_t)cur_seg * D_OUT + colA], run_sum);
        if (colA == 0) atomicAdd(&counts[cur_seg], (float)run_len);
    }
}

__global__ __launch_bounds__(256) void div_kernel(
    const float* __restrict__ sums, const float* __restrict__ counts,
    float* __restrict__ out, int total)
{
    const int i = blockIdx.x * 256 + threadIdx.x;
    if (i < total) out[i] = sums[i] / fmaxf(counts[i >> 7], 1.f);
}

extern "C" void kernel_launch(void* const* d_in, const int* in_sizes, int n_in,
                              void* d_out, int out_size, void* d_ws, size_t ws_size,
                              hipStream_t stream) {
    const float* f   = (const float*)d_in[0];
    const int*   seg = (const int*)  d_in[1];
    const float* W1 = (const float*)d_in[3];
    const float* b1 = (const float*)d_in[4];
    const float* W2 = (const float*)d_in[5];
    const float* b2 = (const float*)d_in[6];
    const float* W3 = (const float*)d_in[7];
    const float* b3 = (const float*)d_in[8];
    float* out = (float*)d_out;

    const int N = in_sizes[0] / D_IN;

    float* sums   = (float*)d_ws;                 // [NSEG * D_OUT]
    float* counts = sums + (size_t)NSEG * D_OUT;  // [NSEG]

    hipMemsetAsync(d_ws, 0, ((size_t)NSEG * D_OUT + NSEG) * sizeof(float), stream);

    const int ntiles  = (N + RT - 1) / RT;
    const int nblocks = (ntiles + TPB - 1) / TPB;
    mlp_seg_mfma<<<nblocks, BLOCK, 0, stream>>>(f, seg, W1, b1, W2, b2, W3, b3,
                                                sums, counts, N, ntiles);

    const int total = NSEG * D_OUT;
    div_kernel<<<(total + 255) / 256, 256, 0, stream>>>(sums, counts, out, total);
}

// Round 5
// 403.884 us; speedup vs baseline: 1.2653x; 1.2653x over previous
//
#include <hip/hip_runtime.h>

constexpr int D_IN  = 64;
constexpr int D_H1  = 32;
constexpr int D_H2  = 64;
constexpr int D_OUT = 128;
constexpr int NSEG  = 8192;

constexpr int BLOCK = 256;       // 4 waves
constexpr int RT    = 64;        // rows per tile
constexpr int TPB   = 8;         // tiles per block -> 1954 blocks

typedef __bf16 bfx8 __attribute__((ext_vector_type(8)));
typedef __bf16 bfx4 __attribute__((ext_vector_type(4)));
typedef float  fx4  __attribute__((ext_vector_type(4)));

// MFMA 16x16x32 bf16 layouts (m89-verified):
//   A: m = lane&15, k = (lane>>4)*8 + j
//   B: n = lane&15, k = (lane>>4)*8 + i   (same lane->element map as A!)
//   D: row(m) = (lane>>4)*4 + reg, col(n) = lane&15
// L1/L2 use SWAPPED operands (W as A, h as B): D = (h*W)^T, so each lane
// holds 4 CONTIGUOUS output features of one data row -> bfx4 epilogue writes.

// Raw barrier with LDS-only ordering: avoids __syncthreads' vmcnt(0) drain
// so prefetch global loads stay in flight across the barrier.
#define BAR_LGKM() do {                                        \
    asm volatile("s_waitcnt lgkmcnt(0)" ::: "memory");         \
    __builtin_amdgcn_s_barrier();                              \
    __builtin_amdgcn_sched_barrier(0);                         \
} while (0)

// __launch_bounds__(256,3): VGPR cap ~170. Demand is ~145 (weights 48 +
// biases 26 + prefetch 16 + accs + scan state). Cap 128 (min-waves=4)
// FORCES SPILL -> 80 MB of scratch traffic, 2x slower (measured r3).
__global__ __launch_bounds__(BLOCK, 3) void mlp_seg_mfma(
    const float* __restrict__ f, const int* __restrict__ seg,
    const float* __restrict__ W1, const float* __restrict__ b1,
    const float* __restrict__ W2, const float* __restrict__ b2,
    const float* __restrict__ W3, const float* __restrict__ b3,
    float* __restrict__ sums, float* __restrict__ counts,
    int N, int ntiles)
{
    __shared__ __align__(16) __bf16 sf [RT * 64];    // 8 KB single buffer (barrier-protected in-place refill)
    __shared__ __align__(16) __bf16 sh1[RT * 32];    // 4 KB
    __shared__ __align__(16) __bf16 sh2[RT * 64];    // 8 KB
    __shared__ __align__(16) __bf16 syT[D_OUT * 64]; // 16 KB transposed [col][row], XOR-swizzled
    __shared__ int sseg[2][RT];                      // seg ids double-buffered (scan reads after BAR2)

    const int tid  = threadIdx.x;
    const int wv   = tid >> 6;
    const int lane = tid & 63;
    const int lr   = lane & 15;
    const int quad = lane >> 4;
    const int m0   = wv * 16;          // this wave's 16-row slice for L1/L2
    const int ar   = m0 + lr;          // data row for this lane (L1/L2)

    // ---- weight fragments + biases -> registers (one-time, L2-cached) ----
    bfx8 fw1[2][2];                    // [ntile][kstep]  W1[64][32]
    #pragma unroll
    for (int j = 0; j < 2; ++j)
        #pragma unroll
        for (int ks = 0; ks < 2; ++ks)
            #pragma unroll
            for (int i = 0; i < 8; ++i)
                fw1[j][ks][i] = (__bf16)W1[(ks*32 + quad*8 + i)*D_H1 + j*16 + lr];

    bfx8 fw2[4];                       // W2[32][64], K=32 single step
    #pragma unroll
    for (int j = 0; j < 4; ++j)
        #pragma unroll
        for (int i = 0; i < 8; ++i)
            fw2[j][i] = (__bf16)W2[(quad*8 + i)*D_H2 + j*16 + lr];

    bfx8 fw3[2][2];                    // W3[64][128], cols wv*32 + j*16 + lr (per-wave col slice)
    #pragma unroll
    for (int j = 0; j < 2; ++j)
        #pragma unroll
        for (int ks = 0; ks < 2; ++ks)
            #pragma unroll
            for (int i = 0; i < 8; ++i)
                fw3[j][ks][i] = (__bf16)W3[(ks*32 + quad*8 + i)*D_OUT + wv*32 + j*16 + lr];

    // biases per-lane for swapped-D layout: feature = j*16 + quad*4 + rg
    fx4 rb1v[2], rb2v[4];
    #pragma unroll
    for (int j = 0; j < 2; ++j)
        #pragma unroll
        for (int rg = 0; rg < 4; ++rg) rb1v[j][rg] = b1[j*16 + quad*4 + rg];
    #pragma unroll
    for (int j = 0; j < 4; ++j)
        #pragma unroll
        for (int rg = 0; rg < 4; ++rg) rb2v[j][rg] = b2[j*16 + quad*4 + rg];
    float rb3[2];
    #pragma unroll
    for (int j = 0; j < 2; ++j) rb3[j] = b3[wv*32 + j*16 + lr];

    // ---- persistent segment-run state (two 128-thread groups) ----
    const int colA = tid & 127;        // owned output column
    const int grp  = tid >> 7;         // group 0: rows 0..31, group 1: rows 32..63
    int   cur_seg = -1;
    float run_sum = 0.f;
    int   run_len = 0;

    const int t0 = blockIdx.x * TPB;
    const int t1 = min(t0 + TPB, ntiles);

    // ---- prologue: stage tile t0 ----
    {
        const int R0 = t0 * RT;
        const float4* f4 = (const float4*)f + (size_t)R0 * 16;
        #pragma unroll
        for (int i = 0; i < 4; ++i) {
            const int idx4 = tid + i * 256;
            float4 qq = make_float4(0.f, 0.f, 0.f, 0.f);
            if ((size_t)R0 * 64 + (size_t)idx4 * 4 < (size_t)N * 64) qq = f4[idx4];
            const int r = idx4 >> 4;
            const int c = (idx4 & 15) * 4;
            bfx4 v;
            v[0] = (__bf16)qq.x; v[1] = (__bf16)qq.y;
            v[2] = (__bf16)qq.z; v[3] = (__bf16)qq.w;
            *(bfx4*)&sf[r*64 + (((c >> 3) ^ (r & 7)) << 3) + (c & 7)] = v;
        }
        if (tid < RT) sseg[0][tid] = (R0 + tid < N) ? seg[R0 + tid] : -2;
    }
    __syncthreads();

    int p = 0;
    for (int t = t0; t < t1; ++t, p ^= 1) {
        const int R0 = t * RT;
        const bool havenext = (t + 1 < t1);

        // ---- issue next tile's global loads EARLY (latency hides under MLP) ----
        float4 q[4];
        int rseg = -2;
        if (havenext) {
            const float4* f4n = (const float4*)f + (size_t)(R0 + RT) * 16;
            #pragma unroll
            for (int i = 0; i < 4; ++i) {
                const int idx4 = tid + i * 256;
                q[i] = make_float4(0.f, 0.f, 0.f, 0.f);
                if ((size_t)(R0 + RT) * 64 + (size_t)idx4 * 4 < (size_t)N * 64)
                    q[i] = f4n[idx4];
            }
            if (tid < RT) rseg = (R0 + RT + tid < N) ? seg[R0 + RT + tid] : -2;
        }

        // ---- L1: h1^T = W1^T * f^T (swapped operands), rows m0..m0+15 ----
        fx4 acc1[2] = {{0,0,0,0},{0,0,0,0}};
        #pragma unroll
        for (int ks = 0; ks < 2; ++ks) {
            bfx8 a = *(const bfx8*)&sf[ar*64 + (((ks*4 + quad) ^ (ar & 7)) << 3)];
            #pragma unroll
            for (int j = 0; j < 2; ++j)
                acc1[j] = __builtin_amdgcn_mfma_f32_16x16x32_bf16(fw1[j][ks], a, acc1[j], 0, 0, 0);
        }
        #pragma unroll
        for (int j = 0; j < 2; ++j) {
            bfx4 w;
            #pragma unroll
            for (int rg = 0; rg < 4; ++rg)
                w[rg] = (__bf16)fmaxf(acc1[j][rg] + rb1v[j][rg], 0.f);
            // feature block b = (j*16+quad*4)>>3, intra-offset (quad&1)*4
            const int b = j*2 + (quad >> 1);
            *(bfx4*)&sh1[ar*32 + ((b ^ (ar & 3)) << 3) + (quad & 1)*4] = w;
        }
        // no barrier: sh1 rows [m0, m0+16) are written and read by this wave only

        // ---- L2: h2^T = W2^T * h1^T (swapped), K=32 single step ----
        fx4 acc2[4] = {{0,0,0,0},{0,0,0,0},{0,0,0,0},{0,0,0,0}};
        {
            bfx8 a = *(const bfx8*)&sh1[ar*32 + ((quad ^ (ar & 3)) << 3)];
            #pragma unroll
            for (int j = 0; j < 4; ++j)
                acc2[j] = __builtin_amdgcn_mfma_f32_16x16x32_bf16(fw2[j], a, acc2[j], 0, 0, 0);
        }
        #pragma unroll
        for (int j = 0; j < 4; ++j) {
            bfx4 w;
            #pragma unroll
            for (int rg = 0; rg < 4; ++rg)
                w[rg] = (__bf16)fmaxf(acc2[j][rg] + rb2v[j][rg], 0.f);
            const int b = j*2 + (quad >> 1);
            *(bfx4*)&sh2[ar*64 + ((b ^ (ar & 7)) << 3) + (quad & 1)*4] = w;
        }

        BAR_LGKM();   // all waves' sh2 writes visible; prefetch loads stay in flight

        // ---- L3: per-wave 32-col slice over ALL 64 rows (unswapped: D rows
        //      contiguous -> bfx4 into transposed syT) ----
        #pragma unroll
        for (int mt = 0; mt < 4; ++mt) {
            fx4 acc3[2] = {{0,0,0,0},{0,0,0,0}};
            const int arow = mt*16 + lr;
            #pragma unroll
            for (int ks = 0; ks < 2; ++ks) {
                bfx8 a = *(const bfx8*)&sh2[arow*64 + (((ks*4 + quad) ^ (arow & 7)) << 3)];
                #pragma unroll
                for (int j = 0; j < 2; ++j)
                    acc3[j] = __builtin_amdgcn_mfma_f32_16x16x32_bf16(a, fw3[j][ks], acc3[j], 0, 0, 0);
            }
            #pragma unroll
            for (int j = 0; j < 2; ++j) {
                bfx4 w;
                #pragma unroll
                for (int rg = 0; rg < 4; ++rg)
                    w[rg] = (__bf16)(acc3[j][rg] + rb3[j]);
                const int col  = wv*32 + j*16 + lr;
                const int row0 = mt*16 + quad*4;   // 4 contiguous rows
                *(bfx4*)&syT[col*64 + (((row0 >> 3) ^ (col & 7)) << 3) + (quad & 1)*4] = w;
            }
        }

        // ---- write prefetched tile in place (sf reads all happened pre-BAR1) ----
        if (havenext) {
            #pragma unroll
            for (int i = 0; i < 4; ++i) {
                const int idx4 = tid + i * 256;
                const int r = idx4 >> 4;
                const int c = (idx4 & 15) * 4;
                bfx4 v;
                v[0] = (__bf16)q[i].x; v[1] = (__bf16)q[i].y;
                v[2] = (__bf16)q[i].z; v[3] = (__bf16)q[i].w;
                *(bfx4*)&sf[r*64 + (((c >> 3) ^ (r & 7)) << 3) + (c & 7)] = v;
            }
            if (tid < RT) sseg[p ^ 1][tid] = rseg;
        }

        BAR_LGKM();   // syT + next-sf writes visible to all waves

        // ---- segment-run accumulation: 4 chunks of 8 rows, vectorized ----
        // seg_ids sorted => s[first]==s[last] implies whole chunk same segment.
        // Next iteration's BAR1 orders these reads against buffer overwrite.
        #pragma unroll
        for (int ch = 0; ch < 4; ++ch) {
            const int r8 = grp*32 + ch*8;
            const bfx8 v8 = *(const bfx8*)&syT[colA*64 + (((grp*4 + ch) ^ (colA & 7)) << 3)];
            const int sA = sseg[p][r8];
            const int sB = sseg[p][r8 + 7];
            if (sA == sB) {                            // fast path (~93% of chunks)
                float sum = 0.f;
                #pragma unroll
                for (int k = 0; k < 8; ++k) sum += (float)v8[k];
                if (sA != cur_seg) {                   // uniform within group
                    if (cur_seg >= 0) {
                        atomicAdd(&sums[(size_t)cur_seg * D_OUT + colA], run_sum);
                        if (colA == 0) atomicAdd(&counts[cur_seg], (float)run_len);
                    }
                    cur_seg = sA; run_sum = sum; run_len = 8;
                } else {
                    run_sum += sum; run_len += 8;
                }
            } else {                                   // boundary chunk: per-row, from regs
                #pragma unroll
                for (int k = 0; k < 8; ++k) {
                    const int s = sseg[p][r8 + k];
                    if (s != cur_seg) {
                        if (cur_seg >= 0) {
                            atomicAdd(&sums[(size_t)cur_seg * D_OUT + colA], run_sum);
                            if (colA == 0) atomicAdd(&counts[cur_seg], (float)run_len);
                        }
                        cur_seg = s; run_sum = 0.f; run_len = 0;
                    }
                    run_sum += (float)v8[k]; run_len++;
                }
            }
        }
    }

    if (cur_seg >= 0) {
        atomicAdd(&sums[(size_t)cur_seg * D_OUT + colA], run_sum);
        if (colA == 0) atomicAdd(&counts[cur_seg], (float)run_len);
    }
}

__global__ __launch_bounds__(256) void div_kernel(
    const float* __restrict__ sums, const float* __restrict__ counts,
    float* __restrict__ out, int total)
{
    const int i = blockIdx.x * 256 + threadIdx.x;
    if (i < total) out[i] = sums[i] / fmaxf(counts[i >> 7], 1.f);
}

extern "C" void kernel_launch(void* const* d_in, const int* in_sizes, int n_in,
                              void* d_out, int out_size, void* d_ws, size_t ws_size,
                              hipStream_t stream) {
    const float* f   = (const float*)d_in[0];
    const int*   seg = (const int*)  d_in[1];
    const float* W1 = (const float*)d_in[3];
    const float* b1 = (const float*)d_in[4];
    const float* W2 = (const float*)d_in[5];
    const float* b2 = (const float*)d_in[6];
    const float* W3 = (const float*)d_in[7];
    const float* b3 = (const float*)d_in[8];
    float* out = (float*)d_out;

    const int N = in_sizes[0] / D_IN;

    float* sums   = (float*)d_ws;                 // [NSEG * D_OUT]
    float* counts = sums + (size_t)NSEG * D_OUT;  // [NSEG]

    hipMemsetAsync(d_ws, 0, ((size_t)NSEG * D_OUT + NSEG) * sizeof(float), stream);

    const int ntiles  = (N + RT - 1) / RT;
    const int nblocks = (ntiles + TPB - 1) / TPB;
    mlp_seg_mfma<<<nblocks, BLOCK, 0, stream>>>(f, seg, W1, b1, W2, b2, W3, b3,
                                                sums, counts, N, ntiles);

    const int total = NSEG * D_OUT;
    div_kernel<<<(total + 255) / 256, 256, 0, stream>>>(sums, counts, out, total);
}